// Round 8
// baseline (365.750 us; speedup 1.0000x reference)
//
#include <hip/hip_runtime.h>
#include <hip/hip_bf16.h>
#include <stdint.h>

#define NTOK 8192   // B*T
#define DDIM 1024
#define LDIM 512
#define VCB  8192
#define MROWS 16384 // NTOK + VCB

typedef unsigned long long u64;
typedef unsigned short ushort_t;
typedef unsigned char u8;
typedef float f32x4 __attribute__((ext_vector_type(4)));
typedef float f32x16 __attribute__((ext_vector_type(16)));
typedef short s16x8 __attribute__((ext_vector_type(8)));
typedef int i32x8 __attribute__((ext_vector_type(8)));

// ---- workspace layout (bytes) ----
// Ab (bf16 cast of [x; codebook], MROWS x DDIM) is dead after k_latent;
// Qb (bf16 normalized latents, MROWS x LDIM = 16.8MB) aliases its start.
#define OFF_AB     0ull                                   // 33.5 MB
#define OFF_QB     0ull                                   // alias (16.8 MB)
#define OFF_P      ((u64)MROWS * DDIM * 2)                // 16.8 MB
#define OFF_QF     (OFF_P + (u64)MROWS * LDIM * 2)        // 8.4 MB fp8
#define OFF_WT     (OFF_QF + (u64)MROWS * 512)            // 2 MB
#define OFF_B2     (OFF_WT + (u64)2 * LDIM * DDIM * 2)    // VCB fp32 (fp8-consistent)
#define OFF_B2B    (OFF_B2 + (u64)VCB * 4)                // VCB fp32 (bf16-consistent)
#define OFF_PART   (OFF_B2B + (u64)VCB * 4)               // NTOK*64 u32 = 2 MB
#define OFF_HIST   (OFF_PART + (u64)NTOK * 64 * 4)        // VCB int
#define OFF_PARTQ  (OFF_HIST + (u64)VCB * 4)              // NTOK fp32
#define OFF_PARTL  (OFF_PARTQ + (u64)NTOK * 4)            // NTOK fp32

__device__ __forceinline__ unsigned key_of(float f) {
  unsigned u = __float_as_uint(f);
  return (u & 0x80000000u) ? ~u : (u | 0x80000000u);
}

__device__ __forceinline__ ushort_t f2bf(float f) {
  unsigned u = __float_as_uint(f);
  unsigned r = (u + 0x7fffu + ((u >> 16) & 1u)) >> 16;
  return (ushort_t)r;
}
__device__ __forceinline__ float bf2f(unsigned b) {
  return __uint_as_float(b << 16);
}
__device__ __forceinline__ unsigned pkbf(float a, float b) {
  __hip_bfloat162 h = __float22bfloat162_rn(make_float2(a, b));
  unsigned r;
  __builtin_memcpy(&r, &h, 4);
  return r;
}

__device__ __forceinline__ void gload_lds16(const void* g, void* l) {
  __builtin_amdgcn_global_load_lds(
      (const __attribute__((address_space(1))) unsigned int*)g,
      (__attribute__((address_space(3))) unsigned int*)l, 16, 0, 0);
}

__device__ __forceinline__ f32x4 mfma16(s16x8 a, s16x8 b, f32x4 c) {
  return __builtin_amdgcn_mfma_f32_16x16x32_bf16(a, b, c, 0, 0, 0);
}

// sum of squares of the 4 fp8 bytes in w (dequantized)
__device__ __forceinline__ float fp8sq4(int w) {
  float f0 = __builtin_amdgcn_cvt_f32_fp8(w, 0);
  float f1 = __builtin_amdgcn_cvt_f32_fp8(w, 1);
  float f2 = __builtin_amdgcn_cvt_f32_fp8(w, 2);
  float f3 = __builtin_amdgcn_cvt_f32_fp8(w, 3);
  return fmaf(f0, f0, fmaf(f1, f1, fmaf(f2, f2, f3 * f3)));
}

// ------ W transpose + bf16 cast: Wt[n][k] = W[k][n]; hist init folded -------
__global__ __launch_bounds__(256)
void k_wt(const float* __restrict__ Wi, const float* __restrict__ Wc,
          ushort_t* __restrict__ Wt, int* __restrict__ hist) {
  __shared__ float tile[32][33];
  const int tx = threadIdx.x, ty = threadIdx.y;
  const int t = ty * 32 + tx;
  const int lb = blockIdx.z * 512 + blockIdx.y * 32 + blockIdx.x;
  if (lb < 32) hist[lb * 256 + t] = 0;
  const float* W = blockIdx.z ? Wc : Wi;
  ushort_t* O = Wt + (blockIdx.z ? (size_t)LDIM * DDIM : 0);
  const int k0 = blockIdx.x * 32, n0 = blockIdx.y * 32;
#pragma unroll
  for (int i = 0; i < 4; ++i)
    tile[ty * 4 + i][tx] = W[(size_t)(k0 + ty * 4 + i) * LDIM + n0 + tx];
  __syncthreads();
#pragma unroll
  for (int i = 0; i < 4; ++i)
    O[(size_t)(n0 + ty * 4 + i) * DDIM + k0 + tx] = f2bf(tile[tx][ty * 4 + i]);
}

// ---------------- cast [x; codebook] fp32 -> Ab bf16 ----------------
__global__ __launch_bounds__(256)
void k_cast(const float* __restrict__ x, const float* __restrict__ cb,
            ushort_t* __restrict__ Ab) {
  size_t i = ((size_t)blockIdx.x * 256 + threadIdx.x) * 8;
  const size_t half = (size_t)NTOK * DDIM;
  const float* src = (i < half) ? (x + i) : (cb + (i - half));
  float4 a = *(const float4*)src;
  float4 b = *(const float4*)(src + 4);
  uint4 o = make_uint4(pkbf(a.x, a.y), pkbf(a.z, a.w),
                       pkbf(b.x, b.y), pkbf(b.z, b.w));
  *(uint4*)&Ab[i] = o;
}

// -------- latent GEMM (MFMA, pure global_load_lds): P = Ab @ Wt^T + b -------
__global__ __launch_bounds__(256)
void k_latent(const ushort_t* __restrict__ Ab, const ushort_t* __restrict__ Wt,
              const float* __restrict__ bi, const float* __restrict__ bc,
              ushort_t* __restrict__ Pb) {
  __shared__ __align__(16) ushort_t As[128 * 32];
  __shared__ __align__(16) ushort_t Bs[128 * 32];
  const int t = threadIdx.x;
  const int wave = t >> 6, lane = t & 63;
  const int col0 = blockIdx.x * 128;   // L index
  const int m0 = blockIdx.y * 128;     // row index in [0, MROWS)
  const bool isCode = (m0 >= NTOK);
  const u8* A = (const u8*)(Ab + (size_t)m0 * DDIM);
  const u8* W = (const u8*)(Wt + (isCode ? (size_t)LDIM * DDIM : 0) +
                            (size_t)col0 * DDIM);
  const float* bias = isCode ? bc : bi;

  const int srow = lane >> 2;
  const int rA = wave * 16 + srow;
  const int rB = 64 + wave * 16 + srow;
  const size_t goA = (size_t)rA * 2048 +
                     (((lane & 3) ^ (rA & 3) ^ ((rA >> 2) & 3)) << 4);
  const size_t goB = (size_t)rB * 2048 +
                     (((lane & 3) ^ (rB & 3) ^ ((rB >> 2) & 3)) << 4);
  u8* lwA0 = (u8*)As + (wave * 16) * 64;
  u8* lwA1 = (u8*)As + (64 + wave * 16) * 64;
  u8* lwB0 = (u8*)Bs + (wave * 16) * 64;
  u8* lwB1 = (u8*)Bs + (64 + wave * 16) * 64;

  const int wm = wave >> 1, wn = wave & 1;
  const int m = lane & 15, q = lane >> 4;
  const int pq = (q ^ (m & 3) ^ ((m >> 2) & 3)) * 16;
  int roffA[4], roffB[4];
#pragma unroll
  for (int i = 0; i < 4; ++i) {
    roffA[i] = (wm * 64 + i * 16 + m) * 64 + pq;
    roffB[i] = (wn * 64 + i * 16 + m) * 64 + pq;
  }

  f32x4 acc[4][4];
#pragma unroll
  for (int i = 0; i < 4; ++i)
#pragma unroll
    for (int j = 0; j < 4; ++j) acc[i][j] = (f32x4)(0.f);

  for (int it = 0; it < DDIM / 32; ++it) {
    const size_t kb = (size_t)it * 64;
    __syncthreads();
    gload_lds16(A + goA + kb, lwA0);
    gload_lds16(A + goB + kb, lwA1);
    gload_lds16(W + goA + kb, lwB0);
    gload_lds16(W + goB + kb, lwB1);
    __syncthreads();
    s16x8 af[4], bfr[4];
#pragma unroll
    for (int i = 0; i < 4; ++i)
      af[i] = *(const s16x8*)((const u8*)As + roffA[i]);
#pragma unroll
    for (int j = 0; j < 4; ++j)
      bfr[j] = *(const s16x8*)((const u8*)Bs + roffB[j]);
#pragma unroll
    for (int i = 0; i < 4; ++i)
#pragma unroll
      for (int j = 0; j < 4; ++j)
        acc[i][j] = mfma16(af[i], bfr[j], acc[i][j]);
  }

  float bv[4];
#pragma unroll
  for (int j = 0; j < 4; ++j) bv[j] = bias[col0 + wn * 64 + j * 16 + m];
#pragma unroll
  for (int i = 0; i < 4; ++i)
#pragma unroll
    for (int j = 0; j < 4; ++j) {
      int col = col0 + wn * 64 + j * 16 + m;
#pragma unroll
      for (int reg = 0; reg < 4; ++reg) {
        int row = m0 + wm * 64 + i * 16 + q * 4 + reg;
        Pb[(size_t)row * LDIM + col] = f2bf(acc[i][j][reg] + bv[j]);
      }
    }
}

// ------ row normalize (1 wave/row, no barriers) -> Qf fp8 + Qb bf16 + b2 ----
__global__ __launch_bounds__(256)
void k_rownorm(const ushort_t* __restrict__ P, u8* __restrict__ Qf,
               ushort_t* __restrict__ Qb, float* __restrict__ b2,
               float* __restrict__ b2b) {
  const int row = blockIdx.x * 4 + (threadIdx.x >> 6);
  const int lane = threadIdx.x & 63;
  uint4 u = *((const uint4*)(P + (size_t)row * LDIM) + lane);
  float v[8];
  v[0] = bf2f(u.x & 0xffffu); v[1] = bf2f(u.x >> 16);
  v[2] = bf2f(u.y & 0xffffu); v[3] = bf2f(u.y >> 16);
  v[4] = bf2f(u.z & 0xffffu); v[5] = bf2f(u.z >> 16);
  v[6] = bf2f(u.w & 0xffffu); v[7] = bf2f(u.w >> 16);
  float s = 0.f;
#pragma unroll
  for (int i = 0; i < 8; ++i) s = fmaf(v[i], v[i], s);
#pragma unroll
  for (int msk = 1; msk < 64; msk <<= 1) s += __shfl_xor(s, msk, 64);
  float rs = (float)(1.0 / sqrt((double)s + 1e-12));
  float qv[8];
#pragma unroll
  for (int i = 0; i < 8; ++i) qv[i] = v[i] * rs;
  // Qb bf16 row-major
  uint4 o = make_uint4(pkbf(qv[0], qv[1]), pkbf(qv[2], qv[3]),
                       pkbf(qv[4], qv[5]), pkbf(qv[6], qv[7]));
  *((uint4*)(Qb + (size_t)row * LDIM) + lane) = o;
  // Qf fp8 interleaved (8 consecutive k -> 8 consecutive bytes at pos p)
  unsigned w0 = (unsigned)__builtin_amdgcn_cvt_pk_fp8_f32(qv[0], qv[1], 0, false);
  w0 = (unsigned)__builtin_amdgcn_cvt_pk_fp8_f32(qv[2], qv[3], (int)w0, true);
  unsigned w1 = (unsigned)__builtin_amdgcn_cvt_pk_fp8_f32(qv[4], qv[5], 0, false);
  w1 = (unsigned)__builtin_amdgcn_cvt_pk_fp8_f32(qv[6], qv[7], (int)w1, true);
  const int k0 = lane * 8, c = k0 >> 6, r = k0 & 63;
  const int p = (r < 32) ? (c * 64 + ((r >> 3) << 4))
                         : (c * 64 + (((r - 32) >> 3) << 4) + 8);
  *(u64*)(Qf + (size_t)row * 512 + p) = ((u64)w1 << 32) | w0;
  if (row >= NTOK) {
    float s8 = fp8sq4((int)w0) + fp8sq4((int)w1);
    float sb = 0.f;
    float g[8];
    g[0] = bf2f(o.x & 0xffffu); g[1] = bf2f(o.x >> 16);
    g[2] = bf2f(o.y & 0xffffu); g[3] = bf2f(o.y >> 16);
    g[4] = bf2f(o.z & 0xffffu); g[5] = bf2f(o.z >> 16);
    g[6] = bf2f(o.w & 0xffffu); g[7] = bf2f(o.w >> 16);
#pragma unroll
    for (int i = 0; i < 8; ++i) sb = fmaf(g[i], g[i], sb);
#pragma unroll
    for (int msk = 1; msk < 64; msk <<= 1) {
      s8 += __shfl_xor(s8, msk, 64);
      sb += __shfl_xor(sb, msk, 64);
    }
    if (lane == 0) {
      b2[row - NTOK] = s8;
      b2b[row - NTOK] = sb;
    }
  }
}

// ------- distance GEMM (MX-fp8 32x32x64, unit scales) + per-chunk argmin ----
// key(n,v) = b2[v] - 2*<Qin[n],Qcb[v]>; packed u32 = (key19 | idx13).
__global__ __launch_bounds__(256)
void k_dist(const u8* __restrict__ Qf, const float* __restrict__ b2,
            unsigned* __restrict__ part) {
  __shared__ __align__(16) u8 S[2][128 * 64];   // As, Bs: 8 KB each
  u8* As = S[0];
  u8* Bs = S[1];
  const int t = threadIdx.x;
  const int wave = t >> 6, lane = t & 63;
  const int v0 = blockIdx.x * 128;
  const int n0 = blockIdx.y * 128;
  const u8* Ga = Qf + (size_t)n0 * 512;
  const u8* Gb = Qf + (size_t)(NTOK + v0) * 512;

  // staging identical to round 6: 64 B/row/iter, XOR-swizzled 16B granules
  const int srow = lane >> 2;
  const int rA = wave * 16 + srow;
  const int rB = 64 + wave * 16 + srow;
  const size_t goA = (size_t)rA * 512 +
                     (((lane & 3) ^ (rA & 3) ^ ((rA >> 2) & 3)) << 4);
  const size_t goB = (size_t)rB * 512 +
                     (((lane & 3) ^ (rB & 3) ^ ((rB >> 2) & 3)) << 4);
  u8* lwA0 = As + (wave * 16) * 64;
  u8* lwA1 = As + (64 + wave * 16) * 64;
  u8* lwB0 = Bs + (wave * 16) * 64;
  u8* lwB1 = Bs + (64 + wave * 16) * 64;

  const int wm = wave >> 1, wn = wave & 1;
  const int c31 = lane & 31, q2 = lane >> 5;
  // frag granule offsets: lane needs source granules {2q2, 2q2+1} of its row,
  // placed in canonical order to cancel the staging XOR
  int roffA[2][2], roffB[2][2];
#pragma unroll
  for (int ti = 0; ti < 2; ++ti) {
    int fr = wm * 64 + ti * 32 + c31;
    int s = (fr & 3) ^ ((fr >> 2) & 3);
    roffA[ti][0] = fr * 64 + (((2 * q2) ^ s) << 4);
    roffA[ti][1] = fr * 64 + (((2 * q2 + 1) ^ s) << 4);
    fr = wn * 64 + ti * 32 + c31;
    s = (fr & 3) ^ ((fr >> 2) & 3);
    roffB[ti][0] = fr * 64 + (((2 * q2) ^ s) << 4);
    roffB[ti][1] = fr * 64 + (((2 * q2 + 1) ^ s) << 4);
  }

  f32x16 acc[4];
#pragma unroll
  for (int i = 0; i < 4; ++i) acc[i] = (f32x16)(0.f);

  for (int it = 0; it < 8; ++it) {
    const int k0 = it * 64;
    __syncthreads();
    gload_lds16(Ga + goA + k0, lwA0);
    gload_lds16(Ga + goB + k0, lwA1);
    gload_lds16(Gb + goA + k0, lwB0);
    gload_lds16(Gb + goB + k0, lwB1);
    __syncthreads();
    i32x8 av[2], bv[2];
#pragma unroll
    for (int ti = 0; ti < 2; ++ti) {
      *(uint4*)&av[ti] = *(const uint4*)(As + roffA[ti][0]);
      *(((uint4*)&av[ti]) + 1) = *(const uint4*)(As + roffA[ti][1]);
      *(uint4*)&bv[ti] = *(const uint4*)(Bs + roffB[ti][0]);
      *(((uint4*)&bv[ti]) + 1) = *(const uint4*)(Bs + roffB[ti][1]);
    }
#pragma unroll
    for (int ti = 0; ti < 2; ++ti)
#pragma unroll
      for (int tj = 0; tj < 2; ++tj)
        acc[ti * 2 + tj] = __builtin_amdgcn_mfma_scale_f32_32x32x64_f8f6f4(
            av[ti], bv[tj], acc[ti * 2 + tj], 0, 0, 0, 127, 0, 127);
  }

  // epilogue: C/D map col=lane&31, row=(reg&3)+8*(reg>>2)+4*q2
  float b2v[2];
  int idv[2];
#pragma unroll
  for (int tj = 0; tj < 2; ++tj) {
    int col = v0 + wn * 64 + tj * 32 + c31;
    b2v[tj] = b2[col];
    idv[tj] = col;
  }
  __syncthreads();
  unsigned* tbl = (unsigned*)S;   // 128 rows x 2 partials
#pragma unroll
  for (int ti = 0; ti < 2; ++ti)
#pragma unroll
    for (int reg = 0; reg < 16; ++reg) {
      float kk0 = fmaf(-2.f, acc[ti * 2 + 0][reg], b2v[0]);
      float kk1 = fmaf(-2.f, acc[ti * 2 + 1][reg], b2v[1]);
      unsigned p0 = (key_of(kk0) & 0xFFFFE000u) | (unsigned)idv[0];
      unsigned p1 = (key_of(kk1) & 0xFFFFE000u) | (unsigned)idv[1];
      unsigned best = (p1 < p0) ? p1 : p0;
#pragma unroll
      for (int msk = 1; msk < 32; msk <<= 1) {
        unsigned o = (unsigned)__shfl_xor((int)best, msk, 32);
        best = (o < best) ? o : best;
      }
      if (c31 == 0) {
        int rl = wm * 64 + ti * 32 + (reg & 3) + 4 * q2 + 8 * (reg >> 2);
        tbl[rl * 2 + wn] = best;
      }
    }
  __syncthreads();
  if (t < 128) {
    unsigned a = tbl[t * 2], b = tbl[t * 2 + 1];
    part[(size_t)(n0 + t) * 64 + blockIdx.x] = (a < b) ? a : b;
  }
}

// -- gather + top-8 select + bf16 rescore + hist + loss partials --
__global__ __launch_bounds__(256)
void k_gather(const unsigned* __restrict__ part, const float* __restrict__ cb,
              const float* __restrict__ x, const ushort_t* __restrict__ P,
              const ushort_t* __restrict__ Qb, const float* __restrict__ b2b,
              float* __restrict__ out, int* __restrict__ hist,
              float* __restrict__ partq, float* __restrict__ partl) {
  const int n = blockIdx.x;
  const int t = threadIdx.x;
  const int lane = t & 63, wid = t >> 6;
  __shared__ float qin[512];
  __shared__ unsigned cand[8];
  __shared__ unsigned wcand[8];
  __shared__ int sIdx;
  __shared__ float rq[4], rl[4];

  unsigned uq = ((const unsigned*)(Qb + (size_t)n * LDIM))[t];
  qin[2 * t] = bf2f(uq & 0xffffu);
  qin[2 * t + 1] = bf2f(uq >> 16);

  if (t < 64) {
    unsigned v = part[(size_t)n * 64 + t];
#pragma unroll
    for (int it = 0; it < 8; ++it) {
      unsigned mn = v;
#pragma unroll
      for (int msk = 1; msk < 64; msk <<= 1) {
        unsigned o = (unsigned)__shfl_xor((int)mn, msk, 64);
        mn = (o < mn) ? o : mn;
      }
      if (t == 0) cand[it] = mn;
      if (v == mn) v = 0xFFFFFFFFu;
    }
  }
  __syncthreads();

  const int c = t >> 5, sl = t & 31;
  const int cidx = (int)(cand[c] & 0x1FFFu);
  const unsigned* crow =
      (const unsigned*)(Qb + (size_t)(NTOK + cidx) * LDIM) + sl * 8;
  uint4 va = *(const uint4*)(crow);
  uint4 vb = *(const uint4*)(crow + 4);
  const float* qs = &qin[sl * 16];
  float dot = 0.f;
  dot = fmaf(bf2f(va.x & 0xffffu), qs[0], dot);
  dot = fmaf(bf2f(va.x >> 16),     qs[1], dot);
  dot = fmaf(bf2f(va.y & 0xffffu), qs[2], dot);
  dot = fmaf(bf2f(va.y >> 16),     qs[3], dot);
  dot = fmaf(bf2f(va.z & 0xffffu), qs[4], dot);
  dot = fmaf(bf2f(va.z >> 16),     qs[5], dot);
  dot = fmaf(bf2f(va.w & 0xffffu), qs[6], dot);
  dot = fmaf(bf2f(va.w >> 16),     qs[7], dot);
  dot = fmaf(bf2f(vb.x & 0xffffu), qs[8], dot);
  dot = fmaf(bf2f(vb.x >> 16),     qs[9], dot);
  dot = fmaf(bf2f(vb.y & 0xffffu), qs[10], dot);
  dot = fmaf(bf2f(vb.y >> 16),     qs[11], dot);
  dot = fmaf(bf2f(vb.z & 0xffffu), qs[12], dot);
  dot = fmaf(bf2f(vb.z >> 16),     qs[13], dot);
  dot = fmaf(bf2f(vb.w & 0xffffu), qs[14], dot);
  dot = fmaf(bf2f(vb.w >> 16),     qs[15], dot);
#pragma unroll
  for (int msk = 1; msk < 32; msk <<= 1) dot += __shfl_xor(dot, msk, 32);
  if (sl == 0) {
    float key = fmaf(-2.f, dot, b2b[cidx]);
    wcand[c] = (key_of(key) & 0xFFFFE000u) | (unsigned)cidx;
  }
  __syncthreads();
  if (t == 0) {
    unsigned mm = wcand[0];
#pragma unroll
    for (int i = 1; i < 8; ++i) mm = (wcand[i] < mm) ? wcand[i] : mm;
    int iv = (int)(mm & 0x1FFFu);
    sIdx = iv;
    atomicAdd(&hist[iv], 1);
  }
  __syncthreads();
  const int iv = sIdx;

  float4 qv = *(const float4*)&cb[(size_t)iv * DDIM + t * 4];
  float4 xv = *(const float4*)&x[(size_t)n * DDIM + t * 4];
  *(float4*)&out[(size_t)n * DDIM + t * 4] = qv;
  float d0 = qv.x - xv.x, d1 = qv.y - xv.y, d2 = qv.z - xv.z, d3 = qv.w - xv.w;
  float sq = d0 * d0 + d1 * d1 + d2 * d2 + d3 * d3;
  unsigned lq = *(const unsigned*)&P[(size_t)(NTOK + iv) * LDIM + t * 2];
  unsigned lx = *(const unsigned*)&P[(size_t)n * LDIM + t * 2];
  float e0 = bf2f(lq & 0xffffu) - bf2f(lx & 0xffffu);
  float e1 = bf2f(lq >> 16) - bf2f(lx >> 16);
  float sl2 = e0 * e0 + e1 * e1;
#pragma unroll
  for (int o = 32; o > 0; o >>= 1) {
    sq += __shfl_down(sq, o, 64);
    sl2 += __shfl_down(sl2, o, 64);
  }
  if (lane == 0) { rq[wid] = sq; rl[wid] = sl2; }
  __syncthreads();
  if (t == 0) {
    partq[n] = rq[0] + rq[1] + rq[2] + rq[3];
    partl[n] = rl[0] + rl[1] + rl[2] + rl[3];
  }
}

// ---------------- finalize scalars ----------------
__global__ __launch_bounds__(1024)
void k_final(const int* __restrict__ hist, const float* __restrict__ partq,
             const float* __restrict__ partl, float* __restrict__ out) {
  const int t = threadIdx.x;
  const int lane = t & 63, wid = t >> 6;  // 16 waves
  float perp = 0.f, usedf = 0.f, sq = 0.f, sl = 0.f;
  for (int v = t; v < VCB; v += 1024) {
    int h = hist[v];
    usedf += (h > 0) ? 1.f : 0.f;
    float p = (float)h * (1.f / (float)NTOK);
    perp -= p * logf(p + 1e-10f);
  }
  for (int n = t; n < NTOK; n += 1024) {
    sq += partq[n];
    sl += partl[n];
  }
#pragma unroll
  for (int o = 32; o > 0; o >>= 1) {
    perp  += __shfl_down(perp, o, 64);
    usedf += __shfl_down(usedf, o, 64);
    sq    += __shfl_down(sq, o, 64);
    sl    += __shfl_down(sl, o, 64);
  }
  __shared__ float red[16][4];
  if (lane == 0) {
    red[wid][0] = perp; red[wid][1] = usedf; red[wid][2] = sq; red[wid][3] = sl;
  }
  __syncthreads();
  if (t == 0) {
    float Pp = 0.f, U = 0.f, SQ = 0.f, SL = 0.f;
    for (int w = 0; w < 16; ++w) {
      Pp += red[w][0]; U += red[w][1]; SQ += red[w][2]; SL += red[w][3];
    }
    float mseq = SQ / (float)((size_t)NTOK * DDIM);
    float msel = SL / (float)((size_t)NTOK * LDIM);
    float loss = 1.25f * mseq + 1.25f * msel + 0.1f * Pp;
    out[(size_t)NTOK * DDIM + 0] = loss;
    out[(size_t)NTOK * DDIM + 1] = expf(Pp);
    out[(size_t)NTOK * DDIM + 2] = U / (float)VCB;
  }
}

extern "C" void kernel_launch(void* const* d_in, const int* in_sizes, int n_in,
                              void* d_out, int out_size, void* d_ws, size_t ws_size,
                              hipStream_t stream) {
  const float* x  = (const float*)d_in[0];
  const float* cb = (const float*)d_in[1];
  const float* Wi = (const float*)d_in[2];
  const float* bi = (const float*)d_in[3];
  const float* Wc = (const float*)d_in[4];
  const float* bc = (const float*)d_in[5];
  float* out = (float*)d_out;
  char* ws = (char*)d_ws;
  ushort_t* Ab   = (ushort_t*)(ws + OFF_AB);
  ushort_t* Qb   = (ushort_t*)(ws + OFF_QB);   // aliases Ab (dead by then)
  ushort_t* P    = (ushort_t*)(ws + OFF_P);
  u8*       Qf   = (u8*)(ws + OFF_QF);
  ushort_t* Wt   = (ushort_t*)(ws + OFF_WT);
  float*    b2   = (float*)(ws + OFF_B2);
  float*    b2b  = (float*)(ws + OFF_B2B);
  unsigned* part = (unsigned*)(ws + OFF_PART);
  int*      hist = (int*)(ws + OFF_HIST);
  float*    partq = (float*)(ws + OFF_PARTQ);
  float*    partl = (float*)(ws + OFF_PARTL);

  hipLaunchKernelGGL(k_wt, dim3(DDIM / 32, LDIM / 32, 2), dim3(32, 8), 0,
                     stream, Wi, Wc, Wt, hist);
  hipLaunchKernelGGL(k_cast, dim3((MROWS * DDIM) / (256 * 8)), dim3(256), 0,
                     stream, x, cb, Ab);
  hipLaunchKernelGGL(k_latent, dim3(LDIM / 128, MROWS / 128), dim3(256), 0,
                     stream, Ab, Wt, bi, bc, P);
  hipLaunchKernelGGL(k_rownorm, dim3(MROWS / 4), dim3(256), 0, stream, P, Qf,
                     Qb, b2, b2b);
  hipLaunchKernelGGL(k_dist, dim3(VCB / 128, NTOK / 128), dim3(256), 0, stream,
                     Qf, b2, part);
  hipLaunchKernelGGL(k_gather, dim3(NTOK), dim3(256), 0, stream, part, cb, x,
                     P, Qb, b2b, out, hist, partq, partl);
  hipLaunchKernelGGL(k_final, dim3(1), dim3(1024), 0, stream, hist, partq,
                     partl, out);
}